// Round 1
// baseline (421.369 us; speedup 1.0000x reference)
//
#include <hip/hip_runtime.h>

#define BATCH 16384
#define DDIM  300
#define NS    5
#define NCTX  10
#define XSTR  (NCTX + 2)
#define D4    75          // 300 floats = 75 float4, rows are 1200B -> 16B aligned
#define NBLK  2048        // partial-sum blocks (8 per CU)

// Kernel 1: one wave per batch row (grid-strided). Lanes own float4 chunks of
// the 300-dim vectors: lane l owns chunk l, and chunk 64+l if l < 11.
__global__ __launch_bounds__(256) void sense_partials(
    const int*   __restrict__ x,
    const float* __restrict__ Wg,
    const float* __restrict__ Ws,
    float*       __restrict__ partial /* [NS][NBLK] */) {
  const int lane = threadIdx.x & 63;
  const int wid  = threadIdx.x >> 6;          // 4 waves per block
  const int gw   = blockIdx.x * 4 + wid;
  const int nw   = NBLK * 4;

  float acc[NS] = {0.f, 0.f, 0.f, 0.f, 0.f};

  for (int b = gw; b < BATCH; b += nw) {
    const int* xr = x + b * XSTR;
    int v = (lane < XSTR) ? xr[lane] : 0;
    const int w0 = __shfl(v, 0);

    // sum_context accumulated into per-lane float4 slices
    float4 sc0 = make_float4(0.f, 0.f, 0.f, 0.f);
    float4 sc1 = make_float4(0.f, 0.f, 0.f, 0.f);
#pragma unroll
    for (int j = 0; j < NCTX; ++j) {
      const int c = __shfl(v, 2 + j);
      const float4* row = (const float4*)Wg + (size_t)c * D4;
      float4 r0 = row[lane];
      sc0.x += r0.x; sc0.y += r0.y; sc0.z += r0.z; sc0.w += r0.w;
      if (lane < D4 - 64) {
        float4 r1 = row[64 + lane];
        sc1.x += r1.x; sc1.y += r1.y; sc1.z += r1.z; sc1.w += r1.w;
      }
    }

    const float4* wrow = (const float4*)Ws + (size_t)w0 * (NS * D4);
#pragma unroll
    for (int s = 0; s < NS; ++s) {
      float4 a0 = wrow[s * D4 + lane];
      float d = a0.x * sc0.x + a0.y * sc0.y + a0.z * sc0.z + a0.w * sc0.w;
      if (lane < D4 - 64) {
        float4 a1 = wrow[s * D4 + 64 + lane];
        d += a1.x * sc1.x + a1.y * sc1.y + a1.z * sc1.z + a1.w * sc1.w;
      }
      acc[s] += d;
    }
  }

  // wave reduction (64 lanes)
#pragma unroll
  for (int s = 0; s < NS; ++s) {
    float t = acc[s];
#pragma unroll
    for (int off = 32; off; off >>= 1) t += __shfl_down(t, off);
    acc[s] = t;
  }

  __shared__ float red[4][NS];
  if (lane == 0) {
#pragma unroll
    for (int s = 0; s < NS; ++s) red[wid][s] = acc[s];
  }
  __syncthreads();
  if (threadIdx.x < NS) {
    float t = red[0][threadIdx.x] + red[1][threadIdx.x] +
              red[2][threadIdx.x] + red[3][threadIdx.x];
    partial[threadIdx.x * NBLK + blockIdx.x] = t;   // s-major for easy reduce
  }
}

// Kernel 2: 5 waves, wave s reduces partial[s][*], writes sigmoid.
__global__ __launch_bounds__(320) void sense_reduce(
    const float* __restrict__ partial, float* __restrict__ out) {
  const int lane = threadIdx.x & 63;
  const int s    = threadIdx.x >> 6;   // 0..4
  float sum = 0.f;
  for (int g = lane; g < NBLK; g += 64) sum += partial[s * NBLK + g];
#pragma unroll
  for (int off = 32; off; off >>= 1) sum += __shfl_down(sum, off);
  if (lane == 0) out[s] = 1.0f / (1.0f + __expf(-sum));
}

extern "C" void kernel_launch(void* const* d_in, const int* in_sizes, int n_in,
                              void* d_out, int out_size, void* d_ws, size_t ws_size,
                              hipStream_t stream) {
  const int*   x  = (const int*)d_in[0];
  const float* Wg = (const float*)d_in[1];
  const float* Ws = (const float*)d_in[2];
  float* partial  = (float*)d_ws;          // NS*NBLK*4 = 40 KB
  float* out      = (float*)d_out;

  sense_partials<<<NBLK, 256, 0, stream>>>(x, Wg, Ws, partial);
  sense_reduce<<<1, 320, 0, stream>>>(partial, out);
}

// Round 2
// 405.654 us; speedup vs baseline: 1.0387x; 1.0387x over previous
//
#include <hip/hip_runtime.h>

typedef float v4f __attribute__((ext_vector_type(4)));

#define BATCH 16384
#define NS    5
#define NCTX  10
#define XSTR  (NCTX + 2)
#define D4    75          // 300 floats = 75 float4; rows are 1200B -> 16B aligned
#define NBLK  2048        // 2048 blocks x 4 waves = 8192 waves; 2 rows per wave

// One wave per PAIR of batch rows, processed interleaved for 2x memory-level
// parallelism. Lanes own float4 chunks: lane l owns chunk l, plus chunk 64+l
// for l < 11. Ws is streamed with non-temporal loads (300 MB, ~no reuse) so it
// doesn't evict the hot 60 MB Wg table from L2/L3.
__global__ __launch_bounds__(256) void sense_partials(
    const int*   __restrict__ x,
    const float* __restrict__ Wg,
    const float* __restrict__ Ws,
    float*       __restrict__ partial /* [NS][NBLK] */) {
  const int lane = threadIdx.x & 63;
  const int wid  = threadIdx.x >> 6;          // 4 waves per block
  const int pair = blockIdx.x * 4 + wid;      // 0..8191
  const int b0   = pair * 2;                  // rows b0, b0+1

  const v4f* Wg4 = (const v4f*)Wg;
  const v4f* Ws4 = (const v4f*)Ws;

  // both rows' x entries in one 24-lane load
  int v = (lane < 2 * XSTR) ? x[(size_t)b0 * XSTR + lane] : 0;
  const int wA = __shfl(v, 0);
  const int wB = __shfl(v, XSTR);

  const v4f* WsA = Ws4 + (size_t)wA * (NS * D4);
  const v4f* WsB = Ws4 + (size_t)wB * (NS * D4);

  const bool hi = (lane < D4 - 64);           // lanes 0..10 own chunk 64+lane

  v4f sA0 = 0.f, sA1 = 0.f, sB0 = 0.f, sB1 = 0.f;
#pragma unroll
  for (int j = 0; j < NCTX; ++j) {
    const int ca = __shfl(v, 2 + j);
    const int cb = __shfl(v, XSTR + 2 + j);
    const v4f* ra = Wg4 + (size_t)ca * D4;
    const v4f* rb = Wg4 + (size_t)cb * D4;
    sA0 += ra[lane];
    sB0 += rb[lane];
    if (hi) {
      sA1 += ra[64 + lane];
      sB1 += rb[64 + lane];
    }
  }

  float acc[NS];
#pragma unroll
  for (int s = 0; s < NS; ++s) {
    v4f a0 = __builtin_nontemporal_load(&WsA[s * D4 + lane]);
    v4f c0 = __builtin_nontemporal_load(&WsB[s * D4 + lane]);
    v4f p  = a0 * sA0 + c0 * sB0;
    if (hi) {
      v4f a1 = __builtin_nontemporal_load(&WsA[s * D4 + 64 + lane]);
      v4f c1 = __builtin_nontemporal_load(&WsB[s * D4 + 64 + lane]);
      p += a1 * sA1 + c1 * sB1;
    }
    acc[s] = p.x + p.y + p.z + p.w;
  }

  // wave reduction (64 lanes)
#pragma unroll
  for (int s = 0; s < NS; ++s) {
    float t = acc[s];
#pragma unroll
    for (int off = 32; off; off >>= 1) t += __shfl_down(t, off);
    acc[s] = t;
  }

  __shared__ float red[4][NS];
  if (lane == 0) {
#pragma unroll
    for (int s = 0; s < NS; ++s) red[wid][s] = acc[s];
  }
  __syncthreads();
  if (threadIdx.x < NS) {
    float t = red[0][threadIdx.x] + red[1][threadIdx.x] +
              red[2][threadIdx.x] + red[3][threadIdx.x];
    partial[threadIdx.x * NBLK + blockIdx.x] = t;   // s-major for easy reduce
  }
}

// Kernel 2: 5 waves, wave s reduces partial[s][*], writes sigmoid.
__global__ __launch_bounds__(320) void sense_reduce(
    const float* __restrict__ partial, float* __restrict__ out) {
  const int lane = threadIdx.x & 63;
  const int s    = threadIdx.x >> 6;   // 0..4
  float sum = 0.f;
  for (int g = lane; g < NBLK; g += 64) sum += partial[s * NBLK + g];
#pragma unroll
  for (int off = 32; off; off >>= 1) sum += __shfl_down(sum, off);
  if (lane == 0) out[s] = 1.0f / (1.0f + __expf(-sum));
}

extern "C" void kernel_launch(void* const* d_in, const int* in_sizes, int n_in,
                              void* d_out, int out_size, void* d_ws, size_t ws_size,
                              hipStream_t stream) {
  const int*   x  = (const int*)d_in[0];
  const float* Wg = (const float*)d_in[1];
  const float* Ws = (const float*)d_in[2];
  float* partial  = (float*)d_ws;          // NS*NBLK*4 = 40 KB
  float* out      = (float*)d_out;

  sense_partials<<<NBLK, 256, 0, stream>>>(x, Wg, Ws, partial);
  sense_reduce<<<1, 320, 0, stream>>>(partial, out);
}